// Round 10
// baseline (466.662 us; speedup 1.0000x reference)
//
#include <hip/hip_runtime.h>
#include <math.h>

#define BB 16
#define DMODEL 2048
#define NHEAD 32
#define SKV 4096
#define HDIM 64
#define BH (BB*NHEAD)   /* 512 */
#define RECS 72         /* floats per wave-record: m, se, pad[6], acc[64] */

typedef float f4 __attribute__((ext_vector_type(4)));

// ---------------------------------------------------------------------------
// partial GEMM: part[tile_y][b][o] = sum_{i in tile of 64} src[b][i]*W[i][o]
// grid (2, 32, nmat), block 256, thread owns 4 consecutive o-columns.
// ---------------------------------------------------------------------------
__global__ __launch_bounds__(256) void gemm_part(
    const float* __restrict__ src,
    const float* __restrict__ Wa, const float* __restrict__ Wb,
    const float* __restrict__ Wc,
    float* __restrict__ pa, float* __restrict__ pb, float* __restrict__ pc) {
  const float* W = (blockIdx.z == 0) ? Wa : ((blockIdx.z == 1) ? Wb : Wc);
  float* part    = (blockIdx.z == 0) ? pa : ((blockIdx.z == 1) ? pb : pc);
  __shared__ float xs[16][64];
  int tid = threadIdx.x;
  int i0 = blockIdx.y * 64;
  int o  = blockIdx.x * 1024 + tid * 4;
  {
    int t = tid * 4;
    int b = t >> 6, i = t & 63;
    *(f4*)&xs[b][i] = *(const f4*)&src[b * DMODEL + i0 + i];
  }
  __syncthreads();
  f4 acc[16];
#pragma unroll
  for (int b = 0; b < 16; ++b) acc[b] = (f4)0.f;
#pragma unroll 8
  for (int i = 0; i < 64; ++i) {
    f4 w = *(const f4*)&W[(size_t)(i0 + i) * DMODEL + o];
#pragma unroll
    for (int b = 0; b < 16; ++b) acc[b] += xs[b][i] * w;
  }
  float* p = part + (size_t)blockIdx.y * (16 * DMODEL) + o;
#pragma unroll
  for (int b = 0; b < 16; ++b) *(f4*)&p[b * DMODEL] = acc[b];
}

// ---------------------------------------------------------------------------
// reduce partials over 32 tiles + bias -> dst.  grid (128, nmat)
// ---------------------------------------------------------------------------
__global__ __launch_bounds__(256) void gemm_reduce(
    const float* __restrict__ pa, const float* __restrict__ pb,
    const float* __restrict__ pc,
    const float* __restrict__ ba, const float* __restrict__ bb,
    const float* __restrict__ bc,
    float* __restrict__ da, float* __restrict__ db, float* __restrict__ dc) {
  const float* p    = (blockIdx.y == 0) ? pa : ((blockIdx.y == 1) ? pb : pc);
  const float* bias = (blockIdx.y == 0) ? ba : ((blockIdx.y == 1) ? bb : bc);
  float* dst        = (blockIdx.y == 0) ? da : ((blockIdx.y == 1) ? db : dc);
  int idx = blockIdx.x * 256 + threadIdx.x;
  float s = bias[idx & (DMODEL - 1)];
#pragma unroll 8
  for (int t = 0; t < 32; ++t) s += p[(size_t)t * (16 * DMODEL) + idx];
  dst[idx] = s;
}

// ---------------------------------------------------------------------------
// Fused K->V stream, ZERO barriers / ZERO LDS. Per block: 256 rows of (b,h).
// Phase A: K copy + scores in regs (row-replicated in the 16-lane group).
// Per-WAVE softmax partials (m_w over the wave's 64 rows, se_w) -- needs only
// shfl, no block reduce, so phase B starts with no vmcnt drain.
// Phase B: V copy + acc += exp(s - m_w) * v; wave writes record
// [m, se, pad, acc[64]]. Combine (exact) is deferred to attn_gemm_part.
// nt hints on all four streams (A/B-confirmed R6/R7: +55us).
// ---------------------------------------------------------------------------
__global__ __launch_bounds__(256) void kv_stream(
    const float* __restrict__ cacheK, const float* __restrict__ cacheV,
    const float* __restrict__ knew, const float* __restrict__ vnew,
    const float* __restrict__ qv, const int* __restrict__ last_pos,
    float* __restrict__ outK, float* __restrict__ outV,
    float* __restrict__ wrec) {
  int bh = blockIdx.x >> 4;
  int j0 = (blockIdx.x & 15) << 8;
  int b = bh >> 5;
  int lp = last_pos[b];
  int tid = threadIdx.x;
  int wave = tid >> 6, lane = tid & 63, q4 = lane >> 4, l16 = lane & 15;
  int rbase = wave * 4 + q4;
  const f4 qf = ((const f4*)(qv + bh * HDIM))[l16];
  const f4 kn = ((const f4*)(knew + bh * HDIM))[l16];
  size_t base = ((size_t)bh * SKV + j0 + rbase) * 16 + l16;
  const f4* K4 = (const f4*)cacheK + base;
  f4* OK4 = (f4*)outK + base;

  // ---- phase A: K stream + scores
  float fv[16];
#pragma unroll
  for (int t = 0; t < 16; ++t) {
    int j = j0 + rbase + t * 16;
    f4 kv = __builtin_nontemporal_load(&K4[t * 256]);
    if (j == lp) kv = kn;
    __builtin_nontemporal_store(kv, &OK4[t * 256]);
    float p = qf.x * kv.x + qf.y * kv.y + qf.z * kv.z + qf.w * kv.w;
    p += __shfl_xor(p, 1);
    p += __shfl_xor(p, 2);
    p += __shfl_xor(p, 4);
    p += __shfl_xor(p, 8);
    fv[t] = (j <= lp) ? p * 0.125f : -1e30f;
  }
  // wave-local max over its 64 rows (4 row-groups x 16 replicas)
  float m = fv[0];
#pragma unroll
  for (int t = 1; t < 16; ++t) m = fmaxf(m, fv[t]);
  m = fmaxf(m, __shfl_xor(m, 16));
  m = fmaxf(m, __shfl_xor(m, 32));
  float se = 0.f;
#pragma unroll
  for (int t = 0; t < 16; ++t) { fv[t] = __expf(fv[t] - m); se += fv[t]; }
  se += __shfl_xor(se, 16);
  se += __shfl_xor(se, 32);

  // ---- phase B: V stream + weighted accumulate (no barrier crossed)
  const f4 vn = ((const f4*)(vnew + bh * HDIM))[l16];
  const f4* V4 = (const f4*)cacheV + base;
  f4* OV4 = (f4*)outV + base;
  f4 acc = (f4)0.f;
#pragma unroll
  for (int t = 0; t < 16; ++t) {
    int j = j0 + rbase + t * 16;
    f4 vv = __builtin_nontemporal_load(&V4[t * 256]);
    if (j == lp) vv = vn;
    __builtin_nontemporal_store(vv, &OV4[t * 256]);
    acc += fv[t] * vv;
  }
  // sum the 4 row-groups: lanes differing in bits 4,5
  acc.x += __shfl_xor(acc.x, 16); acc.x += __shfl_xor(acc.x, 32);
  acc.y += __shfl_xor(acc.y, 16); acc.y += __shfl_xor(acc.y, 32);
  acc.z += __shfl_xor(acc.z, 16); acc.z += __shfl_xor(acc.z, 32);
  acc.w += __shfl_xor(acc.w, 16); acc.w += __shfl_xor(acc.w, 32);
  float* rec = wrec + (size_t)(blockIdx.x * 4 + wave) * RECS;
  if (q4 == 0) *(f4*)&rec[8 + l16 * 4] = acc;   // lanes 0..15: 64B coalesced
  if (lane == 16) { rec[0] = m; rec[1] = se; }
}

// ---------------------------------------------------------------------------
// Wo GEMM; x-staging combines the 64 wave-records of bh=(b,h) exactly:
//   attn[d] = sum_w e^{m_w-M} acc_w[d] / sum_w e^{m_w-M} se_w
// grid (2, 32 heads), block 256 (thread = (batch g, dim-quad u)).
// ---------------------------------------------------------------------------
__global__ __launch_bounds__(256) void attn_gemm_part(
    const float* __restrict__ wrec, const float* __restrict__ Wo,
    float* __restrict__ po) {
  __shared__ float xs[16][64];
  int tid = threadIdx.x;
  int h = blockIdx.y;
  {
    int g = tid >> 4, u = tid & 15;
    const float* r = wrec + (size_t)(g * NHEAD + h) * 64 * RECS;
    float M = -1e30f;
#pragma unroll 8
    for (int s = 0; s < 64; ++s) M = fmaxf(M, r[s * RECS]);
    float D = 0.f;
    f4 a = (f4)0.f;
#pragma unroll 8
    for (int s = 0; s < 64; ++s) {
      float w = __expf(r[s * RECS] - M);
      D += w * r[s * RECS + 1];
      a += w * *(const f4*)&r[s * RECS + 8 + u * 4];
    }
    *(f4*)&xs[g][u * 4] = a * (1.f / D);
  }
  __syncthreads();
  int o = blockIdx.x * 1024 + tid * 4;
  int i0 = h * 64;
  f4 acc[16];
#pragma unroll
  for (int b = 0; b < 16; ++b) acc[b] = (f4)0.f;
#pragma unroll 8
  for (int i = 0; i < 64; ++i) {
    f4 w = *(const f4*)&Wo[(size_t)(i0 + i) * DMODEL + o];
#pragma unroll
    for (int b = 0; b < 16; ++b) acc[b] += xs[b][i] * w;
  }
  float* p = po + (size_t)blockIdx.y * (16 * DMODEL) + o;
#pragma unroll
  for (int b = 0; b < 16; ++b) *(f4*)&p[b * DMODEL] = acc[b];
}

// ---------------------------------------------------------------------------
extern "C" void kernel_launch(void* const* d_in, const int* in_sizes, int n_in,
                              void* d_out, int out_size, void* d_ws, size_t ws_size,
                              hipStream_t stream) {
  const float* x        = (const float*)d_in[0];
  const int*   last_pos = (const int*)d_in[1];
  // d_in[2] = mask (recomputed from last_pos, ignored)
  const float* Wq = (const float*)d_in[3];
  const float* bq = (const float*)d_in[4];
  const float* Wk = (const float*)d_in[5];
  const float* bk = (const float*)d_in[6];
  const float* Wv = (const float*)d_in[7];
  const float* bv = (const float*)d_in[8];
  const float* Wo = (const float*)d_in[9];
  const float* bo = (const float*)d_in[10];
  const float* cacheK = (const float*)d_in[11];
  const float* cacheV = (const float*)d_in[12];

  float* out  = (float*)d_out;                      // 32768
  float* outK = out + (size_t)BB * DMODEL;
  float* outV = outK + (size_t)BH * SKV * HDIM;

  float* ws   = (float*)d_ws;
  float* q    = ws;                                 // 32768
  float* k    = ws + 32768;
  float* v    = ws + 65536;
  // wrec: 8192 blocks * 4 waves * RECS = 2,359,296 floats (after gemms)
  float* wrec = ws + 98304;
  // QKV gemm partials overlap wrec (consumed by gemm_reduce before kv_stream)
  float* pq = ws + 98304;
  float* pk = ws + 98304 + 1048576;
  float* pv = ws + 98304 + 2097152;
  // po placed after wrec (attn_gemm_part reads wrec, writes po: disjoint)
  float* po = ws + 98304 + 2359296;                 // 1,048,576 floats

  gemm_part<<<dim3(2, 32, 3), 256, 0, stream>>>(x, Wq, Wk, Wv, pq, pk, pv);
  gemm_reduce<<<dim3(128, 3), 256, 0, stream>>>(pq, pk, pv, bq, bk, bv, q, k, v);
  kv_stream<<<8192, 256, 0, stream>>>(cacheK, cacheV, k, v, q, last_pos,
                                      outK, outV, wrec);
  attn_gemm_part<<<dim3(2, 32), 256, 0, stream>>>(wrec, Wo, po);
  gemm_reduce<<<dim3(128, 1), 256, 0, stream>>>(po, po, po, bo, bo, bo,
                                                out, out, out);
}